// Round 14
// baseline (241.273 us; speedup 1.0000x reference)
//
#include <hip/hip_runtime.h>
#include <math.h>

#define N_NODES 8192
#define KNN 9
#define XPAD 1040   // padded hw stride (floats) for the candidate panel

// order-preserving float->uint map packed with index: exact (d, idx) lex order
__device__ __forceinline__ unsigned long long packdi(float d, int idx) {
  unsigned int u = __float_as_uint(d);
  u = (u & 0x80000000u) ? ~u : (u | 0x80000000u);
  return ((unsigned long long)u << 32) | (unsigned int)idx;
}

__device__ __forceinline__ void fma44(float (&acc)[4][4], float4 q, float4 c) {
  acc[0][0] = fmaf(q.x, c.x, acc[0][0]); acc[0][1] = fmaf(q.x, c.y, acc[0][1]);
  acc[0][2] = fmaf(q.x, c.z, acc[0][2]); acc[0][3] = fmaf(q.x, c.w, acc[0][3]);
  acc[1][0] = fmaf(q.y, c.x, acc[1][0]); acc[1][1] = fmaf(q.y, c.y, acc[1][1]);
  acc[1][2] = fmaf(q.y, c.z, acc[1][2]); acc[1][3] = fmaf(q.y, c.w, acc[1][3]);
  acc[2][0] = fmaf(q.z, c.x, acc[2][0]); acc[2][1] = fmaf(q.z, c.y, acc[2][1]);
  acc[2][2] = fmaf(q.z, c.z, acc[2][2]); acc[2][3] = fmaf(q.z, c.w, acc[2][3]);
  acc[3][0] = fmaf(q.w, c.x, acc[3][0]); acc[3][1] = fmaf(q.w, c.y, acc[3][1]);
  acc[3][2] = fmaf(q.w, c.z, acc[3][2]); acc[3][3] = fmaf(q.w, c.w, acc[3][3]);
}

// K1: x[B,C,H,W] -> xf[N,C] (LDS tile transpose, coalesced both ways);
// xpad[b][c][1040] = padded re-store of x rows; sq[n] = ||xf[n]||^2; deg = 0.
__global__ __launch_bounds__(256) void k_prep(const float* __restrict__ x,
                                              float* __restrict__ xf,
                                              float* __restrict__ xpad,
                                              float* __restrict__ sq,
                                              int* __restrict__ deg) {
  __shared__ float t[64][65];
  const int b = blockIdx.x >> 4;
  const int hw0 = (blockIdx.x & 15) * 64;
  const int c0 = threadIdx.x >> 6;      // 0..3
  const int hwl = threadIdx.x & 63;
#pragma unroll
  for (int i = 0; i < 16; ++i) {
    int c = i * 4 + c0;
    float v = x[((size_t)(b * 64 + c)) * 1024 + hw0 + hwl];
    t[c][hwl] = v;
    xpad[((size_t)(b * 64 + c)) * XPAD + hw0 + hwl] = v;   // coalesced re-store
  }
  __syncthreads();
  const int wave = threadIdx.x >> 6;    // 0..3
  const int lane = threadIdx.x & 63;    // channel
#pragma unroll
  for (int i = 0; i < 16; ++i) {
    int r = i * 4 + wave;               // hw row within tile
    float v = t[lane][r];
    int n = b * 1024 + hw0 + r;
    xf[(size_t)n * 64 + lane] = v;      // lanes along c -> 256B contiguous
    float s = v * v;
#pragma unroll
    for (int m = 1; m < 64; m <<= 1) s += __shfl_xor(s, m);
    if (lane == 0) sq[n] = s;
  }
  int tid = blockIdx.x * 256 + threadIdx.x;
  if (tid < N_NODES) deg[tid] = 0;
}

// K2 (k_knn2): FUSED distance GEMM + selection. Block = 16 queries x full
// 1024-candidate batch; d2 lives only in a 64KB LDS stash.
// GEMM: 4 supertiles of 256 cands; micro 4q x 4c; depth-8 prefetch via
// NAMED registers h0..h7, manually 8-step-unrolled k-loop.
// Selection (ZERO ARRAYS — R12/R13 counters showed ~1.2KB/thread scratch
// traffic from the p[16]-array Batcher selection): lane loads its 16 stash
// values once into named u64 packs u0..u15 (packdi = exact (d,idx)-lex),
// then 9 rounds of {strict-min over packs > last} + 64-lane argmin. Each
// round emits the next-smallest pack -> exact top_k order incl. ties.
__global__ __launch_bounds__(256, 2) void k_knn2(const float* __restrict__ x,
                                                 const float* __restrict__ xpad,
                                                 const float* __restrict__ sq,
                                                 int* __restrict__ idxf,
                                                 int* __restrict__ deg) {
  __shared__ float Qs[64][16];      // 4KB  K-major query tile
  __shared__ float st[16][1024];    // 64KB d2 stash
  const int t = threadIdx.x;
  const int q0 = blockIdx.x * 16;
  const int b = q0 >> 10;
  const int bstart = b << 10;
  const int lim = (b == 7) ? 1023 : 1024;   // exclude node 8191 (batch 8)

  // stage Q: Qs[k][ql] = x[b][k][(q0-bstart)+ql]
  {
    const float4* xb4 = reinterpret_cast<const float4*>(x) + (size_t)b * 16384;
    const int qoff4 = (q0 - bstart) >> 2;
    int k = t >> 2, q4 = t & 3;
    float4 v = xb4[(size_t)k * 256 + qoff4 + q4];
    *reinterpret_cast<float4*>(&Qs[k][q4 * 4]) = v;
  }
  __syncthreads();

  const int tq = t >> 6;        // wave id 0..3 -> q rows tq*4..+3
  const int tc = t & 63;        // lane -> c cols tc*4..+3 (within supertile)

  float sqq[4];
#pragma unroll
  for (int i = 0; i < 4; ++i) sqq[i] = sq[q0 + tq * 4 + i];

  for (int ct = 0; ct < 4; ++ct) {
    const int cb = ct * 256 + tc * 4;        // col within batch
    float4 csqv = *reinterpret_cast<const float4*>(sq + bstart + cb);

    float acc[4][4];
#pragma unroll
    for (int i = 0; i < 4; ++i)
#pragma unroll
      for (int j = 0; j < 4; ++j) acc[i][j] = 0.f;

    const float* cg = xpad + (size_t)b * (64 * XPAD) + cb;
#define LD(kk) (*reinterpret_cast<const float4*>(cg + (size_t)(kk) * XPAD))
#define QA(kk) (*reinterpret_cast<const float4*>(&Qs[kk][tq * 4]))
    float4 h0 = LD(0), h1 = LD(1), h2 = LD(2), h3 = LD(3);
    float4 h4 = LD(4), h5 = LD(5), h6 = LD(6), h7 = LD(7);
#pragma unroll
    for (int k0 = 0; k0 < 56; k0 += 8) {
      fma44(acc, QA(k0 + 0), h0); h0 = LD(k0 + 8);
      fma44(acc, QA(k0 + 1), h1); h1 = LD(k0 + 9);
      fma44(acc, QA(k0 + 2), h2); h2 = LD(k0 + 10);
      fma44(acc, QA(k0 + 3), h3); h3 = LD(k0 + 11);
      fma44(acc, QA(k0 + 4), h4); h4 = LD(k0 + 12);
      fma44(acc, QA(k0 + 5), h5); h5 = LD(k0 + 13);
      fma44(acc, QA(k0 + 6), h6); h6 = LD(k0 + 14);
      fma44(acc, QA(k0 + 7), h7); h7 = LD(k0 + 15);
    }
    fma44(acc, QA(56), h0); fma44(acc, QA(57), h1);
    fma44(acc, QA(58), h2); fma44(acc, QA(59), h3);
    fma44(acc, QA(60), h4); fma44(acc, QA(61), h5);
    fma44(acc, QA(62), h6); fma44(acc, QA(63), h7);
#undef LD
#undef QA

    // stash d2 (stride-1 float4 rows: canonical conflict-free pattern)
    float csq[4] = {csqv.x, csqv.y, csqv.z, csqv.w};
#pragma unroll
    for (int i = 0; i < 4; ++i) {
      float4 dd;
      dd.x = fmaf(-2.f, acc[i][0], sqq[i] + csq[0]);
      dd.y = fmaf(-2.f, acc[i][1], sqq[i] + csq[1]);
      dd.z = fmaf(-2.f, acc[i][2], sqq[i] + csq[2]);
      dd.w = fmaf(-2.f, acc[i][3], sqq[i] + csq[3]);
      *reinterpret_cast<float4*>(&st[tq * 4 + i][cb]) = dd;
    }
  }
  __syncthreads();

  // selection: wave w -> queries q0 + w*4 .. +3 (no arrays anywhere)
  const int lane = t & 63;
  const int w = t >> 6;
  for (int qq = 0; qq < 4; ++qq) {
    const int q = q0 + w * 4 + qq;

    if (q == N_NODES - 1) {
      // batch 8 = {8191}: self first, then -inf ties filled with indices 0..7
      if (lane < KNN) {
        int nb = (lane == 0) ? (N_NODES - 1) : (lane - 1);
        idxf[q * KNN + lane] = nb;
        if (nb != q) atomicAdd(&deg[nb], 1);
      }
      continue;
    }

    const float4* srow = reinterpret_cast<const float4*>(&st[w * 4 + qq][0]);
    const int c0 = lane * 4;
    float4 v0 = srow[lane];
    float4 v1 = srow[64 + lane];
    float4 v2 = srow[128 + lane];
    float4 v3 = srow[192 + lane];

    unsigned long long u0, u1, u2, u3, u4, u5, u6, u7;
    unsigned long long u8, u9, u10, u11, u12, u13, u14, u15;
    u0  = (c0 + 0 < lim) ? packdi(v0.x, bstart + c0 + 0) : ~0ULL;
    u1  = (c0 + 1 < lim) ? packdi(v0.y, bstart + c0 + 1) : ~0ULL;
    u2  = (c0 + 2 < lim) ? packdi(v0.z, bstart + c0 + 2) : ~0ULL;
    u3  = (c0 + 3 < lim) ? packdi(v0.w, bstart + c0 + 3) : ~0ULL;
    u4  = (c0 + 256 < lim) ? packdi(v1.x, bstart + c0 + 256) : ~0ULL;
    u5  = (c0 + 257 < lim) ? packdi(v1.y, bstart + c0 + 257) : ~0ULL;
    u6  = (c0 + 258 < lim) ? packdi(v1.z, bstart + c0 + 258) : ~0ULL;
    u7  = (c0 + 259 < lim) ? packdi(v1.w, bstart + c0 + 259) : ~0ULL;
    u8  = (c0 + 512 < lim) ? packdi(v2.x, bstart + c0 + 512) : ~0ULL;
    u9  = (c0 + 513 < lim) ? packdi(v2.y, bstart + c0 + 513) : ~0ULL;
    u10 = (c0 + 514 < lim) ? packdi(v2.z, bstart + c0 + 514) : ~0ULL;
    u11 = (c0 + 515 < lim) ? packdi(v2.w, bstart + c0 + 515) : ~0ULL;
    u12 = (c0 + 768 < lim) ? packdi(v3.x, bstart + c0 + 768) : ~0ULL;
    u13 = (c0 + 769 < lim) ? packdi(v3.y, bstart + c0 + 769) : ~0ULL;
    u14 = (c0 + 770 < lim) ? packdi(v3.z, bstart + c0 + 770) : ~0ULL;
    u15 = (c0 + 771 < lim) ? packdi(v3.w, bstart + c0 + 771) : ~0ULL;

    unsigned long long last = 0ULL;   // valid packs are > 0 (finite d2)
#pragma unroll
    for (int r = 0; r < KNN; ++r) {
      unsigned long long cand = ~0ULL;
#define CHK(uu) { unsigned long long pk = (uu); \
                  if (pk > last && pk < cand) cand = pk; }
      CHK(u0) CHK(u1) CHK(u2) CHK(u3) CHK(u4) CHK(u5) CHK(u6) CHK(u7)
      CHK(u8) CHK(u9) CHK(u10) CHK(u11) CHK(u12) CHK(u13) CHK(u14) CHK(u15)
#undef CHK
      unsigned long long m = cand;
#pragma unroll
      for (int msk = 1; msk < 64; msk <<= 1) {
        unsigned long long o = __shfl_xor(m, msk);
        if (o < m) m = o;
      }
      if (lane == r) {
        int bi = (int)(unsigned int)(m & 0xffffffffu);
        idxf[q * KNN + r] = bi;
        if (bi != q) atomicAdd(&deg[bi], 1);
      }
      last = m;                       // next round: strictly greater packs
    }
  }
}

// K3 (fused gather + output GEMM), 16 nodes/block, grid 512 -> 2 blocks/CU.
__global__ __launch_bounds__(256) void k_gout(const float* __restrict__ xf,
                                              const int* __restrict__ idxf,
                                              const int* __restrict__ deg,
                                              const float* __restrict__ W0,
                                              const float* __restrict__ W1,
                                              const float* __restrict__ bias,
                                              float* __restrict__ out) {
  __shared__ float w0[64 * 64];
  __shared__ float w1[64 * 64];
  __shared__ float sx[16 * 68];
  __shared__ float sg[16 * 68];
  const int nb = blockIdx.x * 16;
  const int t = threadIdx.x;

  float4* w04 = reinterpret_cast<float4*>(w0);
  float4* w14 = reinterpret_cast<float4*>(w1);
  const float4* W04 = reinterpret_cast<const float4*>(W0);
  const float4* W14 = reinterpret_cast<const float4*>(W1);
#pragma unroll
  for (int i = 0; i < 4; ++i) { w04[i * 256 + t] = W04[i * 256 + t]; w14[i * 256 + t] = W14[i * 256 + t]; }
  {
    int ln = t >> 4, c4 = t & 15;
    float4 v = reinterpret_cast<const float4*>(xf + (size_t)(nb + ln) * 64)[c4];
    *reinterpret_cast<float4*>(&sx[ln * 68 + c4 * 4]) = v;
  }
  // gather phase: 1 item/thread, item = (node ln, channel-quad c4)
  {
    int ln = t >> 4, c4 = t & 15;
    int n = nb + ln;
    int dt = deg[n];
    float dis_t = dt > 0 ? 1.f / sqrtf((float)dt) : 0.f;
    float ax = 0.f, ay = 0.f, az = 0.f, aw = 0.f;
#pragma unroll
    for (int k = 0; k < 9; ++k) {
      int s = idxf[n * KNN + k];
      if (s == n) continue;                    // self loop: w=0 -> norm 0
      int ds = deg[s];
      float dis_s = ds > 0 ? 1.f / sqrtf((float)ds) : 0.f;
      float w = -dis_s * dis_t;
      float4 v = reinterpret_cast<const float4*>(xf + (size_t)s * 64)[c4];
      ax = fmaf(w, v.x, ax); ay = fmaf(w, v.y, ay);
      az = fmaf(w, v.z, az); aw = fmaf(w, v.w, aw);
    }
    float4 r; r.x = ax; r.y = ay; r.z = az; r.w = aw;
    *reinterpret_cast<float4*>(&sg[ln * 68 + c4 * 4]) = r;
  }
  __syncthreads();

  const int ln2 = t >> 4, o4 = t & 15;
  float4 a0 = reinterpret_cast<const float4*>(bias)[o4];
#pragma unroll
  for (int c = 0; c < 64; ++c) {
    float4 v0 = reinterpret_cast<const float4*>(w0 + c * 64)[o4];
    float4 v1 = reinterpret_cast<const float4*>(w1 + c * 64)[o4];
    float xv = sx[ln2 * 68 + c];
    float gv = sg[ln2 * 68 + c];
    a0.x = fmaf(xv, v0.x, a0.x); a0.y = fmaf(xv, v0.y, a0.y);
    a0.z = fmaf(xv, v0.z, a0.z); a0.w = fmaf(xv, v0.w, a0.w);
    a0.x = fmaf(gv, v1.x, a0.x); a0.y = fmaf(gv, v1.y, a0.y);
    a0.z = fmaf(gv, v1.z, a0.z); a0.w = fmaf(gv, v1.w, a0.w);
  }
  reinterpret_cast<float4*>(out)[(size_t)(nb + ln2) * 16 + o4] = a0;
}

extern "C" void kernel_launch(void* const* d_in, const int* in_sizes, int n_in,
                              void* d_out, int out_size, void* d_ws, size_t ws_size,
                              hipStream_t stream) {
  const float* x    = (const float*)d_in[0];
  const float* W0   = (const float*)d_in[1];
  const float* W1   = (const float*)d_in[2];
  const float* bias = (const float*)d_in[3];
  float* out = (float*)d_out;
  char* ws = (char*)d_ws;

  // workspace layout (total ~4.6MB)
  float* xf   = (float*)(ws);                       // 2,097,152
  float* sq   = (float*)(ws + 2097152);             // 32,768
  int*   deg  = (int*)  (ws + 2129920);             // 32,768
  int*   idxf = (int*)  (ws + 2162688);             // 294,912
  float* xpad = (float*)(ws + 2457600);             // 8*64*1040*4 = 2,129,920

  k_prep<<<128, 256, 0, stream>>>(x, xf, xpad, sq, deg);
  k_knn2<<<512, 256, 0, stream>>>(x, xpad, sq, idxf, deg);
  k_gout<<<512, 256, 0, stream>>>(xf, idxf, deg, W0, W1, bias, out);
}

// Round 15
// 60.391 us; speedup vs baseline: 3.9952x; 3.9952x over previous
//
#include <hip/hip_runtime.h>
#include <math.h>

#define N_NODES 8192
#define KNN 9

// order-preserving float->uint map packed with index: exact (d, idx) lex order
__device__ __forceinline__ unsigned long long packdi(float d, int idx) {
  unsigned int u = __float_as_uint(d);
  u = (u & 0x80000000u) ? ~u : (u | 0x80000000u);
  return ((unsigned long long)u << 32) | (unsigned int)idx;
}

// K1: x[B,C,H,W] -> xf[N,C] via LDS tile transpose (coalesced both ways);
// sq[n] = ||xf[n]||^2 ; zero deg.
__global__ __launch_bounds__(256) void k_prep(const float* __restrict__ x,
                                              float* __restrict__ xf,
                                              float* __restrict__ sq,
                                              int* __restrict__ deg) {
  __shared__ float t[64][65];
  const int b = blockIdx.x >> 4;
  const int hw0 = (blockIdx.x & 15) * 64;
  const int c0 = threadIdx.x >> 6;      // 0..3
  const int hwl = threadIdx.x & 63;
#pragma unroll
  for (int i = 0; i < 16; ++i) {
    int c = i * 4 + c0;
    t[c][hwl] = x[((size_t)(b * 64 + c)) * 1024 + hw0 + hwl];
  }
  __syncthreads();
  const int wave = threadIdx.x >> 6;    // 0..3
  const int lane = threadIdx.x & 63;    // channel
#pragma unroll
  for (int i = 0; i < 16; ++i) {
    int r = i * 4 + wave;               // hw row within tile
    float v = t[lane][r];
    int n = b * 1024 + hw0 + r;
    xf[(size_t)n * 64 + lane] = v;      // lanes along c -> 256B contiguous
    float s = v * v;
#pragma unroll
    for (int m = 1; m < 64; m <<= 1) s += __shfl_xor(s, m);
    if (lane == 0) sq[n] = s;
  }
  int tid = blockIdx.x * 256 + threadIdx.x;
  if (tid < N_NODES) deg[tid] = 0;
}

// K2 (k_dist v2): distance GEMM, ALL global reads LDS-staged exactly once
// per block (R12-14 proved direct-global candidate streaming causes ~490MB
// of L2-miss traffic; R5-R7's staged reads measured 8.4MB total FETCH).
// One 128q x 128c tile per block, K=64. Qs[64][128] 32KB staged once;
// Cs[32][128] 16KB staged per K-half. Micro 8q x 8c (LDS:FMA = 1.5);
// C-fragment cols split {tc*4, 64+tc*4} so LDS reads are 2-way (free).
// d2 written coalesced to global (33.5MB linear; pattern sane in R8-R11).
__global__ __launch_bounds__(256, 2) void k_dist(const float* __restrict__ x,
                                                 const float* __restrict__ sq,
                                                 float* __restrict__ d2g) {
  __shared__ float Qs[64][128];
  __shared__ float Cs[32][128];
  const int t = threadIdx.x;
  const int q0 = blockIdx.x * 128;
  const int b = q0 >> 10;
  const int bstart = b << 10;
  const int cb0 = blockIdx.y * 128;          // col within batch
  const float4* xb4 = reinterpret_cast<const float4*>(x) + (size_t)b * 16384;

  // stage Q tile: Qs[k][ql] = x[b][k][(q0-bstart)+ql]   (coalesced)
  const int qoff4 = (q0 - bstart) >> 2;
#pragma unroll
  for (int i = 0; i < 8; ++i) {
    int idx = i * 256 + t;                   // 0..2047, 32 float4 per k-row
    int k = idx >> 5, c4 = idx & 31;
    float4 v = xb4[(size_t)k * 256 + qoff4 + c4];
    *reinterpret_cast<float4*>(&Qs[k][c4 * 4]) = v;
  }

  const int tq = t >> 4;    // 0..15 -> q rows tq*8..+7
  const int tc = t & 15;    // 0..15 -> c cols {tc*4..+3} U {64+tc*4..+3}

  float acc[8][8];
#pragma unroll
  for (int i = 0; i < 8; ++i)
#pragma unroll
    for (int j = 0; j < 8; ++j) acc[i][j] = 0.f;

  const int cb4 = cb0 >> 2;
#pragma unroll
  for (int kh = 0; kh < 2; ++kh) {
    __syncthreads();                         // Qs ready / prev half's FMA done
#pragma unroll
    for (int i = 0; i < 4; ++i) {
      int idx = i * 256 + t;                 // 0..1023, 32 float4 per k-row
      int k = idx >> 5, c4 = idx & 31;
      float4 v = xb4[(size_t)(kh * 32 + k) * 256 + cb4 + c4];
      *reinterpret_cast<float4*>(&Cs[k][c4 * 4]) = v;
    }
    __syncthreads();                         // Cs ready
#pragma unroll 2
    for (int k = 0; k < 32; ++k) {
      float4 qa = *reinterpret_cast<const float4*>(&Qs[kh * 32 + k][tq * 8]);
      float4 qb = *reinterpret_cast<const float4*>(&Qs[kh * 32 + k][tq * 8 + 4]);
      float4 ca = *reinterpret_cast<const float4*>(&Cs[k][tc * 4]);
      float4 cb = *reinterpret_cast<const float4*>(&Cs[k][64 + tc * 4]);
      float qv[8] = {qa.x, qa.y, qa.z, qa.w, qb.x, qb.y, qb.z, qb.w};
      float cv[8] = {ca.x, ca.y, ca.z, ca.w, cb.x, cb.y, cb.z, cb.w};
#pragma unroll
      for (int i = 0; i < 8; ++i)
#pragma unroll
        for (int j = 0; j < 8; ++j)
          acc[i][j] = fmaf(qv[i], cv[j], acc[i][j]);
    }
  }

  // epilogue: d2 = (sqq + csq) - 2*dot ; two coalesced float4 per row
  float sqq[8], csq[8];
#pragma unroll
  for (int i = 0; i < 8; ++i) sqq[i] = sq[q0 + tq * 8 + i];
  {
    float4 c1 = *reinterpret_cast<const float4*>(sq + bstart + cb0 + tc * 4);
    float4 c2 = *reinterpret_cast<const float4*>(sq + bstart + cb0 + 64 + tc * 4);
    csq[0] = c1.x; csq[1] = c1.y; csq[2] = c1.z; csq[3] = c1.w;
    csq[4] = c2.x; csq[5] = c2.y; csq[6] = c2.z; csq[7] = c2.w;
  }
#pragma unroll
  for (int i = 0; i < 8; ++i) {
    float* orow = d2g + (size_t)(q0 + tq * 8 + i) * 1024 + cb0;
    float4 o1, o2;
    o1.x = fmaf(-2.f, acc[i][0], sqq[i] + csq[0]);
    o1.y = fmaf(-2.f, acc[i][1], sqq[i] + csq[1]);
    o1.z = fmaf(-2.f, acc[i][2], sqq[i] + csq[2]);
    o1.w = fmaf(-2.f, acc[i][3], sqq[i] + csq[3]);
    o2.x = fmaf(-2.f, acc[i][4], sqq[i] + csq[4]);
    o2.y = fmaf(-2.f, acc[i][5], sqq[i] + csq[5]);
    o2.z = fmaf(-2.f, acc[i][6], sqq[i] + csq[6]);
    o2.w = fmaf(-2.f, acc[i][7], sqq[i] + csq[7]);
    *reinterpret_cast<float4*>(orow + tc * 4) = o1;
    *reinterpret_cast<float4*>(orow + 64 + tc * 4) = o2;
  }
}

// K3 (k_sel): one WAVE per query (coalesced: per load-instr the wave reads
// 1KB contiguous of the query's d2 row). 16 named u64 packs (orderedbits::idx),
// 9 rounds of {strict-min over packs > last} + 64-lane argmin = exact
// (d,idx)-lex top_k incl. ties. Writes idxf + deg. (Validated R10/R11.)
__global__ __launch_bounds__(256) void k_sel(const float* __restrict__ d2g,
                                             int* __restrict__ idxf,
                                             int* __restrict__ deg) {
  const int lane = threadIdx.x & 63;
  const int q = blockIdx.x * 4 + (threadIdx.x >> 6);

  if (q == N_NODES - 1) {
    // batch 8 = {8191}: self first, then -inf ties filled with indices 0..7
    if (lane < KNN) {
      int nb = (lane == 0) ? (N_NODES - 1) : (lane - 1);
      idxf[q * KNN + lane] = nb;
      if (nb != q) atomicAdd(&deg[nb], 1);
    }
    return;
  }

  const int bstart = (q >> 10) << 10;
  const int lim = (bstart == 7168) ? 1023 : 1024;   // exclude node 8191
  const float4* row = reinterpret_cast<const float4*>(d2g + (size_t)q * 1024);
  const int c0 = lane * 4;

  float4 v0 = row[lane];
  float4 v1 = row[64 + lane];
  float4 v2 = row[128 + lane];
  float4 v3 = row[192 + lane];

  unsigned long long u0, u1, u2, u3, u4, u5, u6, u7;
  unsigned long long u8, u9, u10, u11, u12, u13, u14, u15;
  u0  = (c0 + 0 < lim) ? packdi(v0.x, bstart + c0 + 0) : ~0ULL;
  u1  = (c0 + 1 < lim) ? packdi(v0.y, bstart + c0 + 1) : ~0ULL;
  u2  = (c0 + 2 < lim) ? packdi(v0.z, bstart + c0 + 2) : ~0ULL;
  u3  = (c0 + 3 < lim) ? packdi(v0.w, bstart + c0 + 3) : ~0ULL;
  u4  = (c0 + 256 < lim) ? packdi(v1.x, bstart + c0 + 256) : ~0ULL;
  u5  = (c0 + 257 < lim) ? packdi(v1.y, bstart + c0 + 257) : ~0ULL;
  u6  = (c0 + 258 < lim) ? packdi(v1.z, bstart + c0 + 258) : ~0ULL;
  u7  = (c0 + 259 < lim) ? packdi(v1.w, bstart + c0 + 259) : ~0ULL;
  u8  = (c0 + 512 < lim) ? packdi(v2.x, bstart + c0 + 512) : ~0ULL;
  u9  = (c0 + 513 < lim) ? packdi(v2.y, bstart + c0 + 513) : ~0ULL;
  u10 = (c0 + 514 < lim) ? packdi(v2.z, bstart + c0 + 514) : ~0ULL;
  u11 = (c0 + 515 < lim) ? packdi(v2.w, bstart + c0 + 515) : ~0ULL;
  u12 = (c0 + 768 < lim) ? packdi(v3.x, bstart + c0 + 768) : ~0ULL;
  u13 = (c0 + 769 < lim) ? packdi(v3.y, bstart + c0 + 769) : ~0ULL;
  u14 = (c0 + 770 < lim) ? packdi(v3.z, bstart + c0 + 770) : ~0ULL;
  u15 = (c0 + 771 < lim) ? packdi(v3.w, bstart + c0 + 771) : ~0ULL;

  unsigned long long last = 0ULL;   // valid packs are > 0 (finite d2)
#pragma unroll
  for (int r = 0; r < KNN; ++r) {
    unsigned long long cand = ~0ULL;
#define CHK(uu) { unsigned long long pk = (uu); \
                  if (pk > last && pk < cand) cand = pk; }
    CHK(u0) CHK(u1) CHK(u2) CHK(u3) CHK(u4) CHK(u5) CHK(u6) CHK(u7)
    CHK(u8) CHK(u9) CHK(u10) CHK(u11) CHK(u12) CHK(u13) CHK(u14) CHK(u15)
#undef CHK
    unsigned long long m = cand;
#pragma unroll
    for (int msk = 1; msk < 64; msk <<= 1) {
      unsigned long long o = __shfl_xor(m, msk);
      if (o < m) m = o;
    }
    if (lane == r) {
      int bi = (int)(unsigned int)(m & 0xffffffffu);
      idxf[q * KNN + r] = bi;
      if (bi != q) atomicAdd(&deg[bi], 1);
    }
    last = m;                       // next round: strictly greater packs
  }
}

// K4 (fused gather + output GEMM), 16 nodes/block, grid 512 -> 2 blocks/CU.
__global__ __launch_bounds__(256) void k_gout(const float* __restrict__ xf,
                                              const int* __restrict__ idxf,
                                              const int* __restrict__ deg,
                                              const float* __restrict__ W0,
                                              const float* __restrict__ W1,
                                              const float* __restrict__ bias,
                                              float* __restrict__ out) {
  __shared__ float w0[64 * 64];
  __shared__ float w1[64 * 64];
  __shared__ float sx[16 * 68];
  __shared__ float sg[16 * 68];
  const int nb = blockIdx.x * 16;
  const int t = threadIdx.x;

  float4* w04 = reinterpret_cast<float4*>(w0);
  float4* w14 = reinterpret_cast<float4*>(w1);
  const float4* W04 = reinterpret_cast<const float4*>(W0);
  const float4* W14 = reinterpret_cast<const float4*>(W1);
#pragma unroll
  for (int i = 0; i < 4; ++i) { w04[i * 256 + t] = W04[i * 256 + t]; w14[i * 256 + t] = W14[i * 256 + t]; }
  {
    int ln = t >> 4, c4 = t & 15;
    float4 v = reinterpret_cast<const float4*>(xf + (size_t)(nb + ln) * 64)[c4];
    *reinterpret_cast<float4*>(&sx[ln * 68 + c4 * 4]) = v;
  }
  // gather phase: 1 item/thread, item = (node ln, channel-quad c4)
  {
    int ln = t >> 4, c4 = t & 15;
    int n = nb + ln;
    int dt = deg[n];
    float dis_t = dt > 0 ? 1.f / sqrtf((float)dt) : 0.f;
    float ax = 0.f, ay = 0.f, az = 0.f, aw = 0.f;
#pragma unroll
    for (int k = 0; k < 9; ++k) {
      int s = idxf[n * KNN + k];
      if (s == n) continue;                    // self loop: w=0 -> norm 0
      int ds = deg[s];
      float dis_s = ds > 0 ? 1.f / sqrtf((float)ds) : 0.f;
      float w = -dis_s * dis_t;
      float4 v = reinterpret_cast<const float4*>(xf + (size_t)s * 64)[c4];
      ax = fmaf(w, v.x, ax); ay = fmaf(w, v.y, ay);
      az = fmaf(w, v.z, az); aw = fmaf(w, v.w, aw);
    }
    float4 r; r.x = ax; r.y = ay; r.z = az; r.w = aw;
    *reinterpret_cast<float4*>(&sg[ln * 68 + c4 * 4]) = r;
  }
  __syncthreads();

  const int ln2 = t >> 4, o4 = t & 15;
  float4 a0 = reinterpret_cast<const float4*>(bias)[o4];
#pragma unroll
  for (int c = 0; c < 64; ++c) {
    float4 v0 = reinterpret_cast<const float4*>(w0 + c * 64)[o4];
    float4 v1 = reinterpret_cast<const float4*>(w1 + c * 64)[o4];
    float xv = sx[ln2 * 68 + c];
    float gv = sg[ln2 * 68 + c];
    a0.x = fmaf(xv, v0.x, a0.x); a0.y = fmaf(xv, v0.y, a0.y);
    a0.z = fmaf(xv, v0.z, a0.z); a0.w = fmaf(xv, v0.w, a0.w);
    a0.x = fmaf(gv, v1.x, a0.x); a0.y = fmaf(gv, v1.y, a0.y);
    a0.z = fmaf(gv, v1.z, a0.z); a0.w = fmaf(gv, v1.w, a0.w);
  }
  reinterpret_cast<float4*>(out)[(size_t)(nb + ln2) * 16 + o4] = a0;
}

extern "C" void kernel_launch(void* const* d_in, const int* in_sizes, int n_in,
                              void* d_out, int out_size, void* d_ws, size_t ws_size,
                              hipStream_t stream) {
  const float* x    = (const float*)d_in[0];
  const float* W0   = (const float*)d_in[1];
  const float* W1   = (const float*)d_in[2];
  const float* bias = (const float*)d_in[3];
  float* out = (float*)d_out;
  char* ws = (char*)d_ws;

  // workspace layout: xf 2MB, sq 32KB, deg 32KB, idxf 288KB, d2g 33.5MB
  float* xf   = (float*)(ws);
  float* sq   = (float*)(ws + 2097152);
  int*   deg  = (int*)  (ws + 2129920);
  int*   idxf = (int*)  (ws + 2162688);
  float* d2g  = (float*)(ws + 2457600);

  k_prep<<<128, 256, 0, stream>>>(x, xf, sq, deg);
  k_dist<<<dim3(64, 8), 256, 0, stream>>>(x, sq, d2g);
  k_sel <<<2048, 256, 0, stream>>>(d2g, idxf, deg);
  k_gout<<<512, 256, 0, stream>>>(xf, idxf, deg, W0, W1, bias, out);
}